// Round 9
// baseline (319.097 us; speedup 1.0000x reference)
//
#include <hip/hip_runtime.h>
#include <hip/hip_bf16.h>

#define BB   4096
#define DD   128
#define NII  50000
#define NT4  782          // ceil(50000/64) 64-col n-tiles
#define CPC  49           // n-tiles per chunk (16 chunks x 49 >= 782)

typedef __attribute__((ext_vector_type(8))) short  bf8_t;   // 8 bf16 in 4 VGPRs
typedef __attribute__((ext_vector_type(4))) float  f4_t;
typedef __attribute__((ext_vector_type(4))) unsigned short us4_t;
typedef __attribute__((ext_vector_type(4))) float  fl4_t;

static __device__ __forceinline__ unsigned short f2bf(float f) {
    unsigned u = __float_as_uint(f);
    u += 0x7fffu + ((u >> 16) & 1u);       // round-to-nearest-even
    return (unsigned short)(u >> 16);
}

static __device__ __forceinline__ void gload_lds16(const void* g, void* lds) {
    __builtin_amdgcn_global_load_lds(
        (const __attribute__((address_space(1))) void*)g,
        (__attribute__((address_space(3))) void*)lds, 16, 0, 0);
}

// ---------------- K1: gather + LN1 + t = nf @ send_W, s2 = t . a2 ----------------
__global__ __launch_bounds__(128) void k1_embed_send(
    const int* __restrict__ uidx, const float* __restrict__ utab,
    const float* __restrict__ g1, const float* __restrict__ b1,
    const float* __restrict__ sendW, const float* __restrict__ senda,
    float* __restrict__ t_out, float* __restrict__ s2_out)
{
    __shared__ float sb[128];
    __shared__ float nf[128];
    const int row = blockIdx.x;
    const int tid = threadIdx.x;
    const long urow = uidx[row];
    const float x = utab[urow * 128 + tid];

    sb[tid] = x; __syncthreads();
    for (int s = 64; s > 0; s >>= 1) { if (tid < s) sb[tid] += sb[tid + s]; __syncthreads(); }
    const float mean = sb[0] * (1.0f / 128.0f); __syncthreads();
    const float dv = x - mean;
    sb[tid] = dv * dv; __syncthreads();
    for (int s = 64; s > 0; s >>= 1) { if (tid < s) sb[tid] += sb[tid + s]; __syncthreads(); }
    const float var = sb[0] * (1.0f / 128.0f);
    const float rs = rsqrtf(var + 1e-5f);
    nf[tid] = dv * rs * g1[tid] + b1[tid];
    __syncthreads();

    float acc = 0.f;
    #pragma unroll 8
    for (int d = 0; d < 128; ++d) acc += nf[d] * sendW[d * 128 + tid];
    t_out[row * 128 + tid] = acc;

    const float p = acc * senda[128 + tid];   // a2 = send_a[128:]
    __syncthreads();
    sb[tid] = p; __syncthreads();
    for (int s = 64; s > 0; s >>= 1) { if (tid < s) sb[tid] += sb[tid + s]; __syncthreads(); }
    if (tid == 0) s2_out[row] = sb[0];
}

// ---------------- K2b: stats (recomputed per block) + weighted column partial sums ----------------
__global__ __launch_bounds__(256) void k2b_colsum(
    const float* __restrict__ t, const float* __restrict__ s2,
    float* __restrict__ partial)
{
    __shared__ float ew[128];
    __shared__ float sb[256];
    const int tid = threadIdx.x;

    float m = -1e30f;
    for (int i = tid; i < BB; i += 256) m = fmaxf(m, s2[i]);
    sb[tid] = m; __syncthreads();
    for (int s = 128; s > 0; s >>= 1) { if (tid < s) sb[tid] = fmaxf(sb[tid], sb[tid + s]); __syncthreads(); }
    m = sb[0]; __syncthreads();

    const int rbase = blockIdx.x * 128;
    if (tid < 128) ew[tid] = __expf(s2[rbase + tid] - m);
    __syncthreads();
    const int col = tid & 127, half = tid >> 7;
    float acc = 0.f;
    for (int j = half; j < 128; j += 2)
        acc += ew[j] * t[(rbase + j) * 128 + col];
    sb[tid] = acc; __syncthreads();
    if (tid < 128) partial[blockIdx.x * 128 + tid] = sb[tid] + sb[tid + 128];
}

// ---------------- K2c: stats + sent -> ap -> LN2 -> t2 -> r = sin(t2) ----------------
__global__ __launch_bounds__(128) void k2c_finish(
    const float* __restrict__ partial, const float* __restrict__ s2,
    const float* __restrict__ anchors, const float* __restrict__ g2,
    const float* __restrict__ b2, const float* __restrict__ recvW,
    float* __restrict__ r_out)
{
    __shared__ float sent[128];
    __shared__ float na_s[128];
    __shared__ float sb[128];
    const int tid = threadIdx.x;

    float m = -1e30f;
    for (int i = tid; i < BB; i += 128) m = fmaxf(m, s2[i]);
    sb[tid] = m; __syncthreads();
    for (int s = 64; s > 0; s >>= 1) { if (tid < s) sb[tid] = fmaxf(sb[tid], sb[tid + s]); __syncthreads(); }
    m = sb[0]; __syncthreads();
    float sum = 0.f;
    for (int i = tid; i < BB; i += 128) sum += __expf(s2[i] - m);
    sb[tid] = sum; __syncthreads();
    for (int s = 64; s > 0; s >>= 1) { if (tid < s) sb[tid] += sb[tid + s]; __syncthreads(); }
    const float S = sb[0]; __syncthreads();

    float acc = 0.f;
    for (int b = 0; b < 32; ++b) acc += partial[b * 128 + tid];
    sent[tid] = acc / S;
    __syncthreads();
    float ap = 0.f;
    for (int c = 0; c < 128; ++c) ap += sent[c] * anchors[tid * 128 + c];
    sb[tid] = ap; __syncthreads();
    for (int s = 64; s > 0; s >>= 1) { if (tid < s) sb[tid] += sb[tid + s]; __syncthreads(); }
    const float mean = sb[0] * (1.0f / 128.0f); __syncthreads();
    const float dv = ap - mean;
    sb[tid] = dv * dv; __syncthreads();
    for (int s = 64; s > 0; s >>= 1) { if (tid < s) sb[tid] += sb[tid + s]; __syncthreads(); }
    const float var = sb[0] * (1.0f / 128.0f);
    const float rs = rsqrtf(var + 1e-5f);
    na_s[tid] = dv * rs * g2[tid] + b2[tid];
    __syncthreads();
    float t2 = 0.f;
    for (int k = 0; k < 128; ++k) t2 += na_s[k] * recvW[k * 128 + tid];
    r_out[tid] = sinf(t2);     // rec row == t2 row (uniform softmax over identical rows)
}

// ---------------- K3: ue = u + r (f32 + bf16 copy), pos gather ----------------
__global__ __launch_bounds__(256) void k3_ue_pos(
    const int* __restrict__ uidx, const float* __restrict__ utab,
    const int* __restrict__ pidx, const float* __restrict__ itab,
    const float* __restrict__ r, float* __restrict__ ue_out,
    float* __restrict__ pos_out, unsigned short* __restrict__ uebf)
{
    const int gid = blockIdx.x * 256 + threadIdx.x;    // 0 .. 524287
    const int i = gid >> 7, d = gid & 127;
    const float rv = r[d];
    const float u = utab[(long)uidx[i] * 128 + d];
    const float ue = u + rv;
    ue_out[gid] = ue;
    uebf[gid] = f2bf(ue);
    pos_out[gid] = itab[(long)pidx[i] * 128 + d];
}

// ---------------- K3b: item_table -> bf16 ----------------
__global__ __launch_bounds__(256) void k3b_cvt_item(
    const float* __restrict__ itab, unsigned short* __restrict__ ibf)
{
    const int gid = blockIdx.x * 256 + threadIdx.x;    // 0 .. 1,599,999 (x4 elems)
    const fl4_t v = *(const fl4_t*)(itab + (long)gid * 4);
    us4_t o;
    o.x = f2bf(v.x); o.y = f2bf(v.y); o.z = f2bf(v.z); o.w = f2bf(v.w);
    *(us4_t*)(ibf + (long)gid * 4) = o;
}

// ---------------- K4 v9: preds = ue @ item^T  (persistent, raw-barrier counted-vmcnt) ----------------
// Grid 16 chunks x 32 m-stripes = 512 blocks = exactly 2/CU (one generation).
// Per block: A-tile 32 KB staged ONCE; loop ~49 steps over 64-col B-tiles, double-buffered
// (2x16 KB). Per step: issue next B-stage -> compute (swapped-operand MFMA, direct dwordx4
// stores) -> s_waitcnt vmcnt(8) (own loads done, stores in flight) -> raw s_barrier.
// No __syncthreads in the loop => no vmcnt(0) drain; loads span barriers (T3/T4 pattern).
// XCD bonus: id%8 partitions chunks -> each XCD's B-range (1.6 MB) + A (1 MB) fit its L2.
__global__ __launch_bounds__(256, 2) void k4_gemm(
    const unsigned short* __restrict__ uebf,
    const unsigned short* __restrict__ ibf,
    float* __restrict__ preds)
{
    __shared__ unsigned short lA[128 * 128];      // 32 KB
    __shared__ unsigned short lB0[64 * 128];      // 16 KB
    __shared__ unsigned short lB1[64 * 128];      // 16 KB

    const int tid = threadIdx.x;
    const int wave = tid >> 6, lane = tid & 63;
    const int l15 = lane & 15, kg = lane >> 4;    // kg 0..3
    const int chunk = blockIdx.x;                 // 0..15  (x fastest -> XCD owns 2 chunks)
    const int mstripe = blockIdx.y;               // 0..31
    const int base = chunk * CPC;
    const int ns = min(CPC, NT4 - base);
    const int row0 = mstripe * 128;

    // ---- stage A once (XOR-swizzled source, linear LDS dest)
    #pragma unroll
    for (int i = 0; i < 8; ++i) {
        const int o = (i * 256 + tid) * 16, r = o >> 8, ch = (o >> 4) & 15, sw = ch ^ (r & 15);
        gload_lds16(uebf + (size_t)(row0 + r) * 128 + sw * 8,
                    (char*)lA + i * 4096 + wave * 1024);
    }
    // ---- stage B[0] -> lB0
    {
        const int c0 = base * 64;
        #pragma unroll
        for (int i = 0; i < 4; ++i) {
            const int o = (i * 256 + tid) * 16, r = o >> 8, ch = (o >> 4) & 15, sw = ch ^ (r & 15);
            const int bc = (c0 + r) < NII ? (c0 + r) : (NII - 1);
            gload_lds16(ibf + (size_t)bc * 128 + sw * 8,
                        (char*)lB0 + i * 4096 + wave * 1024);
        }
    }
    asm volatile("s_waitcnt vmcnt(0)" ::: "memory");
    __builtin_amdgcn_sched_barrier(0);
    __builtin_amdgcn_s_barrier();

    const int wr = wave >> 1, wc = wave & 1;      // wave tile: 64M x 32N

    for (int j = 0; j < ns; ++j) {
        // ---- issue next B-stage into the other buffer (overlaps this step's compute+stores)
        if (j + 1 < ns) {
            const int c0n = (base + j + 1) * 64;
            char* dst = (char*)((j & 1) ? lB0 : lB1);
            #pragma unroll
            for (int i = 0; i < 4; ++i) {
                const int o = (i * 256 + tid) * 16, r = o >> 8, ch = (o >> 4) & 15, sw = ch ^ (r & 15);
                const int bc = (c0n + r) < NII ? (c0n + r) : (NII - 1);
                gload_lds16(ibf + (size_t)bc * 128 + sw * 8, dst + i * 4096 + wave * 1024);
            }
        }

        const unsigned short* bb = (j & 1) ? lB1 : lB0;

        f4_t acc[4][2];
        #pragma unroll
        for (int m = 0; m < 4; ++m)
            #pragma unroll
            for (int n = 0; n < 2; ++n) acc[m][n] = (f4_t){0.f, 0.f, 0.f, 0.f};

        #pragma unroll
        for (int kk = 0; kk < 4; ++kk) {          // K step of 32
            const int c = kk * 4 + kg;
            bf8_t a[4], b[2];
            #pragma unroll
            for (int m = 0; m < 4; ++m) {
                const int r = wr * 64 + m * 16 + l15;
                a[m] = *(const bf8_t*)((const char*)lA + r * 256 + (c ^ (r & 15)) * 16);
            }
            #pragma unroll
            for (int n = 0; n < 2; ++n) {
                const int r = wc * 32 + n * 16 + l15;
                b[n] = *(const bf8_t*)((const char*)bb + r * 256 + (c ^ (r & 15)) * 16);
            }
            #pragma unroll
            for (int m = 0; m < 4; ++m)
                #pragma unroll
                for (int n = 0; n < 2; ++n)
                    acc[m][n] = __builtin_amdgcn_mfma_f32_16x16x32_bf16(b[n], a[m], acc[m][n], 0, 0, 0);
        }

        // ---- direct store: lane (kg,l15) holds preds[row ..+l15][cols ..+kg*4 ..+3]
        const int col0 = (base + j) * 64;
        #pragma unroll
        for (int m = 0; m < 4; ++m) {
            const long grow = row0 + wr * 64 + m * 16 + l15;
            #pragma unroll
            for (int n = 0; n < 2; ++n) {
                const int gcol = col0 + wc * 32 + n * 16 + kg * 4;
                if (gcol < NII)                   // NII%4==0 -> gcol<NII => gcol+3<NII
                    *(fl4_t*)(preds + grow * NII + gcol) = acc[m][n];
            }
        }

        // ---- pipeline sync: own next-B loads done (8 newer stores may stay in flight),
        //      then raw barrier (all waves' loads landed; prev-buffer reads drained).
        asm volatile("s_waitcnt vmcnt(8)" ::: "memory");
        __builtin_amdgcn_sched_barrier(0);
        __builtin_amdgcn_s_barrier();
    }
}

extern "C" void kernel_launch(void* const* d_in, const int* in_sizes, int n_in,
                              void* d_out, int out_size, void* d_ws, size_t ws_size,
                              hipStream_t stream) {
    const int*   uidx   = (const int*)  d_in[0];
    const int*   pidx   = (const int*)  d_in[1];
    const float* utab   = (const float*)d_in[2];
    const float* itab   = (const float*)d_in[3];
    const float* g1     = (const float*)d_in[4];
    const float* b1     = (const float*)d_in[5];
    const float* sendW  = (const float*)d_in[6];
    const float* senda  = (const float*)d_in[7];
    const float* anchors= (const float*)d_in[8];
    const float* g2     = (const float*)d_in[9];
    const float* b2     = (const float*)d_in[10];
    const float* recvW  = (const float*)d_in[11];
    // d_in[12] (recv_a) provably unused: second fca's softmax weights are exactly uniform.

    char* ws = (char*)d_ws;
    float* t_ws    = (float*)(ws + 0);              // 4096*128*4 = 2,097,152
    float* s2_ws   = (float*)(ws + 2097152);        // 16,384
    float* part_ws = (float*)(ws + 2113600);        // 32*128*4 = 16,384
    float* r_ws    = (float*)(ws + 2129984);        // 512
    unsigned short* uebf = (unsigned short*)(ws + 2130496);   // 1,048,576
    unsigned short* ibf  = (unsigned short*)(ws + 3179072);   // 12,800,000 -> ends ~15.98 MB

    float* preds   = (float*)d_out;
    float* ue_out  = preds + (long)BB * NII;
    float* pos_out = ue_out + BB * DD;

    k3b_cvt_item<<<6250, 256, 0, stream>>>(itab, ibf);
    k1_embed_send<<<4096, 128, 0, stream>>>(uidx, utab, g1, b1, sendW, senda, t_ws, s2_ws);
    k2b_colsum<<<32, 256, 0, stream>>>(t_ws, s2_ws, part_ws);
    k2c_finish<<<1, 128, 0, stream>>>(part_ws, s2_ws, anchors, g2, b2, recvW, r_ws);
    k3_ue_pos<<<2048, 256, 0, stream>>>(uidx, utab, pidx, itab, r_ws, ue_out, pos_out, uebf);
    k4_gemm<<<dim3(16, 32, 1), 256, 0, stream>>>(uebf, ibf, preds);
}

// Round 10
// 243.357 us; speedup vs baseline: 1.3112x; 1.3112x over previous
//
#include <hip/hip_runtime.h>
#include <hip/hip_bf16.h>

#define BB   4096
#define DD   128
#define NII  50000

typedef __attribute__((ext_vector_type(8))) short  bf8_t;   // 8 bf16 in 4 VGPRs
typedef __attribute__((ext_vector_type(4))) float  f4_t;
typedef __attribute__((ext_vector_type(4))) unsigned short us4_t;
typedef __attribute__((ext_vector_type(4))) float  fl4_t;

static __device__ __forceinline__ unsigned short f2bf(float f) {
    unsigned u = __float_as_uint(f);
    u += 0x7fffu + ((u >> 16) & 1u);       // round-to-nearest-even
    return (unsigned short)(u >> 16);
}

static __device__ __forceinline__ void gload_lds16(const void* g, void* lds) {
    __builtin_amdgcn_global_load_lds(
        (const __attribute__((address_space(1))) void*)g,
        (__attribute__((address_space(3))) void*)lds, 16, 0, 0);
}

// ---------------- K1: gather + LN1 + t = nf @ send_W, s2 = t . a2 ----------------
__global__ __launch_bounds__(128) void k1_embed_send(
    const int* __restrict__ uidx, const float* __restrict__ utab,
    const float* __restrict__ g1, const float* __restrict__ b1,
    const float* __restrict__ sendW, const float* __restrict__ senda,
    float* __restrict__ t_out, float* __restrict__ s2_out)
{
    __shared__ float sb[128];
    __shared__ float nf[128];
    const int row = blockIdx.x;
    const int tid = threadIdx.x;
    const long urow = uidx[row];
    const float x = utab[urow * 128 + tid];

    sb[tid] = x; __syncthreads();
    for (int s = 64; s > 0; s >>= 1) { if (tid < s) sb[tid] += sb[tid + s]; __syncthreads(); }
    const float mean = sb[0] * (1.0f / 128.0f); __syncthreads();
    const float dv = x - mean;
    sb[tid] = dv * dv; __syncthreads();
    for (int s = 64; s > 0; s >>= 1) { if (tid < s) sb[tid] += sb[tid + s]; __syncthreads(); }
    const float var = sb[0] * (1.0f / 128.0f);
    const float rs = rsqrtf(var + 1e-5f);
    nf[tid] = dv * rs * g1[tid] + b1[tid];
    __syncthreads();

    float acc = 0.f;
    #pragma unroll 8
    for (int d = 0; d < 128; ++d) acc += nf[d] * sendW[d * 128 + tid];
    t_out[row * 128 + tid] = acc;

    const float p = acc * senda[128 + tid];   // a2 = send_a[128:]
    __syncthreads();
    sb[tid] = p; __syncthreads();
    for (int s = 64; s > 0; s >>= 1) { if (tid < s) sb[tid] += sb[tid + s]; __syncthreads(); }
    if (tid == 0) s2_out[row] = sb[0];
}

// ---------------- K2b: stats (recomputed per block) + weighted column partial sums ----------------
__global__ __launch_bounds__(256) void k2b_colsum(
    const float* __restrict__ t, const float* __restrict__ s2,
    float* __restrict__ partial)
{
    __shared__ float ew[128];
    __shared__ float sb[256];
    const int tid = threadIdx.x;

    float m = -1e30f;
    for (int i = tid; i < BB; i += 256) m = fmaxf(m, s2[i]);
    sb[tid] = m; __syncthreads();
    for (int s = 128; s > 0; s >>= 1) { if (tid < s) sb[tid] = fmaxf(sb[tid], sb[tid + s]); __syncthreads(); }
    m = sb[0]; __syncthreads();

    const int rbase = blockIdx.x * 128;
    if (tid < 128) ew[tid] = __expf(s2[rbase + tid] - m);
    __syncthreads();
    const int col = tid & 127, half = tid >> 7;
    float acc = 0.f;
    for (int j = half; j < 128; j += 2)
        acc += ew[j] * t[(rbase + j) * 128 + col];
    sb[tid] = acc; __syncthreads();
    if (tid < 128) partial[blockIdx.x * 128 + tid] = sb[tid] + sb[tid + 128];
}

// ---------------- K2c: stats + sent -> ap -> LN2 -> t2 -> r = sin(t2) ----------------
__global__ __launch_bounds__(128) void k2c_finish(
    const float* __restrict__ partial, const float* __restrict__ s2,
    const float* __restrict__ anchors, const float* __restrict__ g2,
    const float* __restrict__ b2, const float* __restrict__ recvW,
    float* __restrict__ r_out)
{
    __shared__ float sent[128];
    __shared__ float na_s[128];
    __shared__ float sb[128];
    const int tid = threadIdx.x;

    float m = -1e30f;
    for (int i = tid; i < BB; i += 128) m = fmaxf(m, s2[i]);
    sb[tid] = m; __syncthreads();
    for (int s = 64; s > 0; s >>= 1) { if (tid < s) sb[tid] = fmaxf(sb[tid], sb[tid + s]); __syncthreads(); }
    m = sb[0]; __syncthreads();
    float sum = 0.f;
    for (int i = tid; i < BB; i += 128) sum += __expf(s2[i] - m);
    sb[tid] = sum; __syncthreads();
    for (int s = 64; s > 0; s >>= 1) { if (tid < s) sb[tid] += sb[tid + s]; __syncthreads(); }
    const float S = sb[0]; __syncthreads();

    float acc = 0.f;
    for (int b = 0; b < 32; ++b) acc += partial[b * 128 + tid];
    sent[tid] = acc / S;
    __syncthreads();
    float ap = 0.f;
    for (int c = 0; c < 128; ++c) ap += sent[c] * anchors[tid * 128 + c];
    sb[tid] = ap; __syncthreads();
    for (int s = 64; s > 0; s >>= 1) { if (tid < s) sb[tid] += sb[tid + s]; __syncthreads(); }
    const float mean = sb[0] * (1.0f / 128.0f); __syncthreads();
    const float dv = ap - mean;
    sb[tid] = dv * dv; __syncthreads();
    for (int s = 64; s > 0; s >>= 1) { if (tid < s) sb[tid] += sb[tid + s]; __syncthreads(); }
    const float var = sb[0] * (1.0f / 128.0f);
    const float rs = rsqrtf(var + 1e-5f);
    na_s[tid] = dv * rs * g2[tid] + b2[tid];
    __syncthreads();
    float t2 = 0.f;
    for (int k = 0; k < 128; ++k) t2 += na_s[k] * recvW[k * 128 + tid];
    r_out[tid] = sinf(t2);     // rec row == t2 row (uniform softmax over identical rows)
}

// ---------------- K3: ue = u + r (f32 + bf16 copy), pos gather ----------------
__global__ __launch_bounds__(256) void k3_ue_pos(
    const int* __restrict__ uidx, const float* __restrict__ utab,
    const int* __restrict__ pidx, const float* __restrict__ itab,
    const float* __restrict__ r, float* __restrict__ ue_out,
    float* __restrict__ pos_out, unsigned short* __restrict__ uebf)
{
    const int gid = blockIdx.x * 256 + threadIdx.x;    // 0 .. 524287
    const int i = gid >> 7, d = gid & 127;
    const float rv = r[d];
    const float u = utab[(long)uidx[i] * 128 + d];
    const float ue = u + rv;
    ue_out[gid] = ue;
    uebf[gid] = f2bf(ue);
    pos_out[gid] = itab[(long)pidx[i] * 128 + d];
}

// ---------------- K3b: item_table -> bf16 ----------------
__global__ __launch_bounds__(256) void k3b_cvt_item(
    const float* __restrict__ itab, unsigned short* __restrict__ ibf)
{
    const int gid = blockIdx.x * 256 + threadIdx.x;    // 0 .. 1,599,999 (x4 elems)
    const fl4_t v = *(const fl4_t*)(itab + (long)gid * 4);
    us4_t o;
    o.x = f2bf(v.x); o.y = f2bf(v.y); o.z = f2bf(v.z); o.w = f2bf(v.w);
    *(us4_t*)(ibf + (long)gid * 4) = o;
}

// ---------------- K4 v10: preds = ue @ item^T  (256x256 tile, 8 waves, 128 KB LDS) ----------------
// Staging ratio 0.5 (128 KB staged per 256 KB output) vs v4's 1.0 -> per-CU read traffic
// halves. Single-stage -> sync -> compute -> direct swapped-operand stores (1 KB/row
// contiguous per block). Grid n-fastest (dense write stream, v4's proven order).
__global__ __launch_bounds__(512, 2) void k4_gemm(
    const unsigned short* __restrict__ uebf,
    const unsigned short* __restrict__ ibf,
    float* __restrict__ preds)
{
    __shared__ unsigned short lA[256 * 128];   // 64 KB: 256 M-rows x 256 B
    __shared__ unsigned short lB[256 * 128];   // 64 KB: 256 N-cols x 256 B

    const int tid = threadIdx.x;
    const int wave = tid >> 6, lane = tid & 63;
    const int l15 = lane & 15, kg = lane >> 4;       // kg 0..3
    const int col0 = blockIdx.x * 256;               // N tile (fastest-varying)
    const int row0 = blockIdx.y * 256;               // M tile

    // ---- stage A and B (64 KB each): 8 instrs each, 8 KB per instr (512 thr x 16 B)
    #pragma unroll
    for (int i = 0; i < 8; ++i) {
        const int o  = (i * 512 + tid) * 16;         // linear LDS byte offset this lane fills
        const int r  = o >> 8;                       // tile-local row (256 B rows), 0..255
        const int ch = (o >> 4) & 15;                // physical 16 B chunk
        const int sw = ch ^ (r & 15);                // logical chunk to fetch (XOR swizzle)
        gload_lds16(uebf + (size_t)(row0 + r) * 128 + sw * 8,
                    (char*)lA + i * 8192 + wave * 1024);
        const int bc = (col0 + r) < NII ? (col0 + r) : (NII - 1);
        gload_lds16(ibf + (size_t)bc * 128 + sw * 8,
                    (char*)lB + i * 8192 + wave * 1024);
    }

    const int wr = wave >> 2, wcn = wave & 3;        // 2x4 wave grid: wave tile 128M x 64N

    f4_t acc[8][4];
    #pragma unroll
    for (int m = 0; m < 8; ++m)
        #pragma unroll
        for (int n = 0; n < 4; ++n) acc[m][n] = (f4_t){0.f, 0.f, 0.f, 0.f};

    __syncthreads();

    #pragma unroll
    for (int kk = 0; kk < 4; ++kk) {                 // K step of 32
        const int c = kk * 4 + kg;                   // logical 16 B chunk within row
        bf8_t a[8], b[4];
        #pragma unroll
        for (int m = 0; m < 8; ++m) {
            const int r = wr * 128 + m * 16 + l15;
            a[m] = *(const bf8_t*)((const char*)lA + r * 256 + (c ^ (r & 15)) * 16);
        }
        #pragma unroll
        for (int n = 0; n < 4; ++n) {
            const int r = wcn * 64 + n * 16 + l15;
            b[n] = *(const bf8_t*)((const char*)lB + r * 256 + (c ^ (r & 15)) * 16);
        }
        #pragma unroll
        for (int m = 0; m < 8; ++m)
            #pragma unroll
            for (int n = 0; n < 4; ++n)
                acc[m][n] = __builtin_amdgcn_mfma_f32_16x16x32_bf16(b[n], a[m], acc[m][n], 0, 0, 0);
    }

    // ---- direct store (swapped operands): lane (kg,l15) holds
    //      preds[row0+wr*128+m*16+l15][col0+wcn*64+n*16+kg*4 .. +3]
    #pragma unroll
    for (int m = 0; m < 8; ++m) {
        const long grow = row0 + wr * 128 + m * 16 + l15;
        #pragma unroll
        for (int n = 0; n < 4; ++n) {
            const int gcol = col0 + wcn * 64 + n * 16 + kg * 4;
            if (gcol < NII)                          // NII%4==0 -> gcol<NII => gcol+3<NII
                *(fl4_t*)(preds + grow * NII + gcol) = acc[m][n];
        }
    }
}

extern "C" void kernel_launch(void* const* d_in, const int* in_sizes, int n_in,
                              void* d_out, int out_size, void* d_ws, size_t ws_size,
                              hipStream_t stream) {
    const int*   uidx   = (const int*)  d_in[0];
    const int*   pidx   = (const int*)  d_in[1];
    const float* utab   = (const float*)d_in[2];
    const float* itab   = (const float*)d_in[3];
    const float* g1     = (const float*)d_in[4];
    const float* b1     = (const float*)d_in[5];
    const float* sendW  = (const float*)d_in[6];
    const float* senda  = (const float*)d_in[7];
    const float* anchors= (const float*)d_in[8];
    const float* g2     = (const float*)d_in[9];
    const float* b2     = (const float*)d_in[10];
    const float* recvW  = (const float*)d_in[11];
    // d_in[12] (recv_a) provably unused: second fca's softmax weights are exactly uniform.

    char* ws = (char*)d_ws;
    float* t_ws    = (float*)(ws + 0);              // 4096*128*4 = 2,097,152
    float* s2_ws   = (float*)(ws + 2097152);        // 16,384
    float* part_ws = (float*)(ws + 2113600);        // 32*128*4 = 16,384
    float* r_ws    = (float*)(ws + 2129984);        // 512
    unsigned short* uebf = (unsigned short*)(ws + 2130496);   // 1,048,576
    unsigned short* ibf  = (unsigned short*)(ws + 3179072);   // 12,800,000 -> ends ~15.98 MB

    float* preds   = (float*)d_out;
    float* ue_out  = preds + (long)BB * NII;
    float* pos_out = ue_out + BB * DD;

    k3b_cvt_item<<<6250, 256, 0, stream>>>(itab, ibf);
    k1_embed_send<<<4096, 128, 0, stream>>>(uidx, utab, g1, b1, sendW, senda, t_ws, s2_ws);
    k2b_colsum<<<32, 256, 0, stream>>>(t_ws, s2_ws, part_ws);
    k2c_finish<<<1, 128, 0, stream>>>(part_ws, s2_ws, anchors, g2, b2, recvW, r_ws);
    k3_ue_pos<<<2048, 256, 0, stream>>>(uidx, utab, pidx, itab, r_ws, ue_out, pos_out, uebf);
    k4_gemm<<<dim3(196, 16, 1), 512, 0, stream>>>(uebf, ibf, preds);
}